// Round 3
// baseline (149.886 us; speedup 1.0000x reference)
//
#include <hip/hip_runtime.h>

typedef __attribute__((ext_vector_type(8))) short short8;
typedef __attribute__((ext_vector_type(4))) float float4v;
typedef __attribute__((ext_vector_type(4))) unsigned short us4;

namespace {
constexpr int NG   = 16;    // groups
constexpr int LSEQ = 4096;
constexpr int CIN  = 1024;
constexpr int IPG  = 64;
constexpr int OPG  = 64;
constexpr int KT   = 5;
constexpr int ROWS_PER_CHUNK = 128;
constexpr int CHUNKS = 4;
constexpr int ROWS_PER_BLOCK = ROWS_PER_CHUNK * CHUNKS;  // 512
constexpr int SW_STRIDE  = 328;                // 320 + 8 pad (breaks 640B stride)
constexpr int SIN_STRIDE = 72;                 // 64 + 8 pad (breaks 128B stride)
constexpr int SIN_ROWS   = ROWS_PER_CHUNK + KT - 1;  // 132
}

__device__ __forceinline__ unsigned short f2bf(float f) {
  unsigned int u = __builtin_bit_cast(unsigned int, f);
  u += 0x7fffu + ((u >> 16) & 1u);   // RNE (inputs are finite; no NaN guard needed)
  return (unsigned short)(u >> 16);
}

__global__ __launch_bounds__(256, 2) void mconv_f32_mfma(
    const float* __restrict__ gin,   // fp32, (4,4096,1024)
    const int* __restrict__ gpos,    // int32, (4,4096)
    const float* __restrict__ gwt,   // fp32, (16,64,64,5)
    float* __restrict__ gout) {      // fp32, (4,4096,16,64)
  __shared__ __align__(16) unsigned short sW[OPG * SW_STRIDE];       // 41984 B
  __shared__ __align__(16) unsigned short sIn[SIN_ROWS * SIN_STRIDE];// 19008 B
  __shared__ unsigned char sMask[ROWS_PER_CHUNK * KT];               //   640 B

  const int tid  = threadIdx.x;
  const int wave = tid >> 6;
  const int lane = tid & 63;
  const int quad = lane >> 4;
  const int l16  = lane & 15;

  const int g  = blockIdx.y;
  const int b  = blockIdx.z;
  const int tile0 = blockIdx.x * ROWS_PER_BLOCK;
  const int bL = b * LSEQ;

  // ---- stage weights once: sW[o*328 + k*64 + i] = bf16(W[g][o][i][k])  (B^T rows)
  {
    const float* wg = gwt + (size_t)g * (OPG * IPG * KT);
    for (int u = tid; u < (OPG * IPG * KT) / 4; u += 256) {
      const int base = u * 4;                 // 4 consecutive (i,k) in one o
      float4v v = *(const float4v*)(wg + base);
      int o = base / (IPG * KT);
      int r = base - o * (IPG * KT);
      int i = r / KT;
      int k = r - i * KT;
      int addr = o * SW_STRIDE + k * IPG + i;
      #pragma unroll
      for (int t = 0; t < 4; ++t) {
        sW[addr] = f2bf(v[t]);
        ++k; addr += IPG;
        if (k == KT) { k = 0; ++i; addr -= KT * IPG - 1; }
      }
    }
  }

  const short8 zero8 = {0, 0, 0, 0, 0, 0, 0, 0};
  const float4v zf = {0.f, 0.f, 0.f, 0.f};

  for (int ch = 0; ch < CHUNKS; ++ch) {
    const int l0 = tile0 + ch * ROWS_PER_CHUNK;
    __syncthreads();  // prev chunk's LDS reads done before restage (also fences sW)

    // ---- masks: sMask[lr*5+tap] = (pos[l+tap-2] == pos[l]+tap-2) && in-range
    for (int t = tid; t < ROWS_PER_CHUNK * KT; t += 256) {
      const int lr  = t / KT;
      const int tap = t - lr * KT;
      const int l   = l0 + lr;
      const int lsrc = l + tap - 2;
      int ok = 0;
      if (lsrc >= 0 && lsrc < LSEQ)
        ok = (gpos[bL + lsrc] == gpos[bL + l] + (tap - 2));
      sMask[t] = (unsigned char)ok;
    }

    // ---- input rows [l0-2, l0+130): fp32 -> bf16, zero OOB rows
    for (int u = tid; u < SIN_ROWS * 16; u += 256) {
      const int r  = u >> 4;
      const int c4 = u & 15;
      const int l  = l0 - 2 + r;
      us4 w = {0, 0, 0, 0};
      if (l >= 0 && l < LSEQ) {
        float4v v = *(const float4v*)(gin + (size_t)(bL + l) * CIN + g * IPG + c4 * 4);
        w[0] = f2bf(v[0]); w[1] = f2bf(v[1]); w[2] = f2bf(v[2]); w[3] = f2bf(v[3]);
      }
      *(us4*)(&sIn[r * SIN_STRIDE + c4 * 4]) = w;
    }
    __syncthreads();

    float4v acc[2][4];
    #pragma unroll
    for (int mm = 0; mm < 2; ++mm)
      #pragma unroll
      for (int nt = 0; nt < 4; ++nt)
        acc[mm][nt] = zf;

    const int m0 = wave * 32 + l16;   // local output row, m-tile 0
    const int m1 = m0 + 16;           // m-tile 1

    #pragma unroll
    for (int tap = 0; tap < KT; ++tap) {
      const bool msk0 = sMask[m0 * KT + tap] != 0;
      const bool msk1 = sMask[m1 * KT + tap] != 0;
      #pragma unroll
      for (int h = 0; h < 2; ++h) {
        const int kk = tap * IPG + h * 32 + quad * 8;
        // B frags: B[k][n], lane holds n=l16, k contiguous -> sW row read
        const short8 b0 = *(const short8*)(&sW[(0 * 16 + l16) * SW_STRIDE + kk]);
        const short8 b1 = *(const short8*)(&sW[(1 * 16 + l16) * SW_STRIDE + kk]);
        const short8 b2 = *(const short8*)(&sW[(2 * 16 + l16) * SW_STRIDE + kk]);
        const short8 b3 = *(const short8*)(&sW[(3 * 16 + l16) * SW_STRIDE + kk]);
        // A frags: A[m=l16][k=quad*8+j] -> contiguous 8 bf16 from sIn row m+tap
        const int ci = h * 32 + quad * 8;
        short8 a0 = *(const short8*)(&sIn[(m0 + tap) * SIN_STRIDE + ci]);
        short8 a1 = *(const short8*)(&sIn[(m1 + tap) * SIN_STRIDE + ci]);
        if (!msk0) a0 = zero8;
        if (!msk1) a1 = zero8;
        acc[0][0] = __builtin_amdgcn_mfma_f32_16x16x32_bf16(a0, b0, acc[0][0], 0, 0, 0);
        acc[0][1] = __builtin_amdgcn_mfma_f32_16x16x32_bf16(a0, b1, acc[0][1], 0, 0, 0);
        acc[0][2] = __builtin_amdgcn_mfma_f32_16x16x32_bf16(a0, b2, acc[0][2], 0, 0, 0);
        acc[0][3] = __builtin_amdgcn_mfma_f32_16x16x32_bf16(a0, b3, acc[0][3], 0, 0, 0);
        acc[1][0] = __builtin_amdgcn_mfma_f32_16x16x32_bf16(a1, b0, acc[1][0], 0, 0, 0);
        acc[1][1] = __builtin_amdgcn_mfma_f32_16x16x32_bf16(a1, b1, acc[1][1], 0, 0, 0);
        acc[1][2] = __builtin_amdgcn_mfma_f32_16x16x32_bf16(a1, b2, acc[1][2], 0, 0, 0);
        acc[1][3] = __builtin_amdgcn_mfma_f32_16x16x32_bf16(a1, b3, acc[1][3], 0, 0, 0);
      }
    }

    // ---- epilogue: C/D layout col=lane&15 (=o within n-tile), row=quad*4+reg
    #pragma unroll
    for (int mm = 0; mm < 2; ++mm) {
      const int lrow = l0 + wave * 32 + mm * 16 + quad * 4;
      #pragma unroll
      for (int reg = 0; reg < 4; ++reg) {
        float* orow = gout + ((size_t)(bL + lrow + reg) * NG + g) * OPG;
        #pragma unroll
        for (int nt = 0; nt < 4; ++nt)
          orow[nt * 16 + l16] = acc[mm][nt][reg];
      }
    }
  }
}

extern "C" void kernel_launch(void* const* d_in, const int* in_sizes, int n_in,
                              void* d_out, int out_size, void* d_ws, size_t ws_size,
                              hipStream_t stream) {
  (void)in_sizes; (void)n_in; (void)out_size; (void)d_ws; (void)ws_size;
  const float* gin  = (const float*)d_in[0];
  const int*   gpos = (const int*)d_in[1];
  const float* gwt  = (const float*)d_in[2];
  float*       gout = (float*)d_out;
  dim3 grid(LSEQ / ROWS_PER_BLOCK, NG, 4);   // 8 x 16 x 4 = 512 blocks
  dim3 block(256);
  hipLaunchKernelGGL(mconv_f32_mfma, grid, block, 0, stream,
                     gin, gpos, gwt, gout);
}

// Round 4
// 132.384 us; speedup vs baseline: 1.1322x; 1.1322x over previous
//
#include <hip/hip_runtime.h>

typedef __attribute__((ext_vector_type(8))) short short8;
typedef __attribute__((ext_vector_type(4))) float float4v;
typedef __attribute__((ext_vector_type(4))) unsigned short us4;

namespace {
constexpr int NG   = 16;
constexpr int LSEQ = 4096;
constexpr int CIN  = 1024;
constexpr int IPG  = 64;
constexpr int OPG  = 64;
constexpr int KT   = 5;
constexpr int ROWS = 128;                 // rows per block (main kernel)
constexpr int SIN_STRIDE = 72;            // shorts; 144 B rows (16B aligned)
constexpr int SIN_ROWS   = ROWS + KT - 1; // 132
constexpr int KSTEPS = 10;                // 320 K / 32
constexpr size_t WFRAG_SHORTS = (size_t)NG * 4 * KSTEPS * 512;  // 327,680
constexpr size_t WFRAG_BYTES  = WFRAG_SHORTS * 2;               // 655,360
}

__device__ __forceinline__ unsigned short f2bf(float f) {
  unsigned int u = __builtin_bit_cast(unsigned int, f);
  u += 0x7fffu + ((u >> 16) & 1u);   // RNE (inputs finite)
  return (unsigned short)(u >> 16);
}

// ---------------- prep: W (16,64,64,5) fp32 -> d_ws bf16 in B-frag layout ----
// frag(g,t,ks) tile of 512 shorts: element[n*32 + quad*8 + j] =
//   bf16( W[g][o=t*16+n][i=(ks&1)*32+quad*8+j][tap=ks>>1] )
__global__ __launch_bounds__(256) void wprep(const float* __restrict__ gwt,
                                             unsigned short* __restrict__ wfrag) {
  const int u = blockIdx.x * 256 + threadIdx.x;           // 40960 threads
  const int E    = u * 8;
  const int tile = E >> 9;
  const int w9   = E & 511;
  const int n    = w9 >> 5;
  const int quad = (w9 & 31) >> 3;
  const int ks   = tile % KSTEPS;
  const int tt   = tile / KSTEPS;
  const int t    = tt & 3;
  const int g    = tt >> 2;
  const int tap  = ks >> 1;
  const int h    = ks & 1;
  const int o    = t * 16 + n;
  const float* src = gwt + (((size_t)(g * 64 + o) * 64) + h * 32 + quad * 8) * KT + tap;
  short8 v;
  #pragma unroll
  for (int j = 0; j < 8; ++j)
    v[j] = (short)f2bf(src[j * KT]);
  *(short8*)(wfrag + E) = v;
}

// ---------------- main: 128 rows x 64 outs per block, 2x2 wave split --------
__global__ __launch_bounds__(256, 4) void mconv_main(
    const float* __restrict__ gin,            // (4,4096,1024) fp32
    const int* __restrict__ gpos,             // (4,4096)
    const unsigned short* __restrict__ wfrag, // bf16 frag buffer
    float* __restrict__ gout) {               // (4,4096,16,64) fp32
  __shared__ __align__(16) unsigned short sIn[SIN_ROWS * SIN_STRIDE]; // 19008 B
  __shared__ unsigned char sMaskB[ROWS];                              //   128 B

  const int tid  = threadIdx.x;
  const int wv   = tid >> 6;
  const int lane = tid & 63;
  const int quad = lane >> 4;
  const int l16  = lane & 15;
  const int wm   = wv & 1;        // M half: rows [wm*64, wm*64+64)
  const int wn   = wv >> 1;       // N half: cols [wn*32, wn*32+32)

  const int g  = blockIdx.y;
  const int b  = blockIdx.z;
  const int l0 = blockIdx.x * ROWS;
  const int bL = b * LSEQ;

  // ---- stage input rows [l0-2, l0+130): fp32->bf16, column-swizzled by (r&3)*16
  for (int u = tid; u < SIN_ROWS * 16; u += 256) {
    const int r  = u >> 4;
    const int c4 = u & 15;
    const int l  = l0 - 2 + r;
    us4 w = {0, 0, 0, 0};
    if (l >= 0 && l < LSEQ) {
      float4v v = *(const float4v*)(gin + (size_t)(bL + l) * CIN + g * IPG + c4 * 4);
      w[0] = f2bf(v[0]); w[1] = f2bf(v[1]); w[2] = f2bf(v[2]); w[3] = f2bf(v[3]);
    }
    const int p = (c4 * 4 + ((r & 3) << 4)) & 63;
    *(us4*)(&sIn[r * SIN_STRIDE + p]) = w;
  }

  // ---- masks: one 5-bit byte per row
  if (tid < ROWS) {
    const int l = l0 + tid;
    const int pc = gpos[bL + l];
    unsigned int mbits = 0;
    #pragma unroll
    for (int tap = 0; tap < KT; ++tap) {
      const int lsrc = l + tap - 2;
      int ok = 0;
      if (lsrc >= 0 && lsrc < LSEQ)
        ok = (gpos[bL + lsrc] == pc + (tap - 2));
      mbits |= (unsigned int)ok << tap;
    }
    sMaskB[tid] = (unsigned char)mbits;
  }
  __syncthreads();

  // ---- per-lane mask bytes for the 4 m-tiles
  int mb[4];
  #pragma unroll
  for (int mt = 0; mt < 4; ++mt)
    mb[mt] = sMaskB[wm * 64 + mt * 16 + l16];

  // ---- B-frag bases (register-resident, prefetch depth 1)
  const int laneoff = l16 * 32 + quad * 8;
  const unsigned short* wb0 = wfrag + (size_t)((g * 4 + wn * 2) * KSTEPS) * 512 + laneoff;
  const unsigned short* wb1 = wb0 + (size_t)KSTEPS * 512;

  const short8 zero8 = {0, 0, 0, 0, 0, 0, 0, 0};
  const float4v zf = {0.f, 0.f, 0.f, 0.f};
  float4v acc[4][2];
  #pragma unroll
  for (int mt = 0; mt < 4; ++mt) { acc[mt][0] = zf; acc[mt][1] = zf; }

  short8 bc0 = *(const short8*)(wb0);
  short8 bc1 = *(const short8*)(wb1);

  #pragma unroll 2
  for (int ks = 0; ks < KSTEPS; ++ks) {
    const int ksn = (ks + 1 < KSTEPS) ? ks + 1 : KSTEPS - 1;
    short8 bn0 = *(const short8*)(wb0 + ksn * 512);
    short8 bn1 = *(const short8*)(wb1 + ksn * 512);
    const int tap = ks >> 1;
    const int h   = ks & 1;
    const int s   = h * 32 + quad * 8;
    #pragma unroll
    for (int mt = 0; mt < 4; ++mt) {
      const int r  = wm * 64 + mt * 16 + l16 + tap;     // sIn row (halo-offset)
      const int sp = (s + ((r & 3) << 4)) & 63;
      short8 a = *(const short8*)(&sIn[r * SIN_STRIDE + sp]);
      if (!((mb[mt] >> tap) & 1)) a = zero8;
      acc[mt][0] = __builtin_amdgcn_mfma_f32_16x16x32_bf16(a, bc0, acc[mt][0], 0, 0, 0);
      acc[mt][1] = __builtin_amdgcn_mfma_f32_16x16x32_bf16(a, bc1, acc[mt][1], 0, 0, 0);
    }
    bc0 = bn0; bc1 = bn1;
  }

  // ---- epilogue: C/D layout col=l16, row=quad*4+reg
  #pragma unroll
  for (int mt = 0; mt < 4; ++mt) {
    const int lrow = l0 + wm * 64 + mt * 16 + quad * 4;
    #pragma unroll
    for (int reg = 0; reg < 4; ++reg) {
      float* orow = gout + (size_t)(bL + lrow + reg) * CIN + g * OPG + wn * 32;
      orow[l16]      = acc[mt][0][reg];
      orow[16 + l16] = acc[mt][1][reg];
    }
  }
}

// ---------------- fallback (known-good R3 kernel, used if ws too small) -----
namespace fb {
constexpr int ROWS_PER_CHUNK = 128;
constexpr int CHUNKS = 4;
constexpr int ROWS_PER_BLOCK = 512;
constexpr int SW_STRIDE  = 328;
constexpr int FSIN_STRIDE = 72;
constexpr int FSIN_ROWS   = 132;
}

__global__ __launch_bounds__(256, 2) void mconv_f32_mfma(
    const float* __restrict__ gin, const int* __restrict__ gpos,
    const float* __restrict__ gwt, float* __restrict__ gout) {
  using namespace fb;
  __shared__ __align__(16) unsigned short sW[OPG * SW_STRIDE];
  __shared__ __align__(16) unsigned short sIn[FSIN_ROWS * FSIN_STRIDE];
  __shared__ unsigned char sMask[ROWS_PER_CHUNK * KT];

  const int tid  = threadIdx.x;
  const int wave = tid >> 6;
  const int lane = tid & 63;
  const int quad = lane >> 4;
  const int l16  = lane & 15;
  const int g  = blockIdx.y;
  const int b  = blockIdx.z;
  const int tile0 = blockIdx.x * ROWS_PER_BLOCK;
  const int bL = b * LSEQ;

  {
    const float* wg = gwt + (size_t)g * (OPG * IPG * KT);
    for (int u = tid; u < (OPG * IPG * KT) / 4; u += 256) {
      const int base = u * 4;
      float4v v = *(const float4v*)(wg + base);
      int o = base / (IPG * KT);
      int r = base - o * (IPG * KT);
      int i = r / KT;
      int k = r - i * KT;
      int addr = o * SW_STRIDE + k * IPG + i;
      #pragma unroll
      for (int t = 0; t < 4; ++t) {
        sW[addr] = f2bf(v[t]);
        ++k; addr += IPG;
        if (k == KT) { k = 0; ++i; addr -= KT * IPG - 1; }
      }
    }
  }
  const short8 zero8 = {0,0,0,0,0,0,0,0};
  const float4v zf = {0.f,0.f,0.f,0.f};
  for (int ch = 0; ch < CHUNKS; ++ch) {
    const int l0 = tile0 + ch * ROWS_PER_CHUNK;
    __syncthreads();
    for (int t = tid; t < ROWS_PER_CHUNK * KT; t += 256) {
      const int lr = t / KT, tap = t - lr * KT, l = l0 + lr, lsrc = l + tap - 2;
      int ok = 0;
      if (lsrc >= 0 && lsrc < LSEQ) ok = (gpos[bL + lsrc] == gpos[bL + l] + (tap - 2));
      sMask[t] = (unsigned char)ok;
    }
    for (int u = tid; u < FSIN_ROWS * 16; u += 256) {
      const int r = u >> 4, c4 = u & 15, l = l0 - 2 + r;
      us4 w = {0,0,0,0};
      if (l >= 0 && l < LSEQ) {
        float4v v = *(const float4v*)(gin + (size_t)(bL + l) * CIN + g * IPG + c4 * 4);
        w[0]=f2bf(v[0]); w[1]=f2bf(v[1]); w[2]=f2bf(v[2]); w[3]=f2bf(v[3]);
      }
      *(us4*)(&sIn[r * FSIN_STRIDE + c4 * 4]) = w;
    }
    __syncthreads();
    float4v acc[2][4];
    #pragma unroll
    for (int mm = 0; mm < 2; ++mm)
      #pragma unroll
      for (int nt = 0; nt < 4; ++nt) acc[mm][nt] = zf;
    const int m0 = wave * 32 + l16, m1 = m0 + 16;
    #pragma unroll
    for (int tap = 0; tap < KT; ++tap) {
      const bool msk0 = sMask[m0 * KT + tap] != 0;
      const bool msk1 = sMask[m1 * KT + tap] != 0;
      #pragma unroll
      for (int h = 0; h < 2; ++h) {
        const int kk = tap * IPG + h * 32 + quad * 8;
        const short8 b0 = *(const short8*)(&sW[(0*16 + l16) * SW_STRIDE + kk]);
        const short8 b1 = *(const short8*)(&sW[(1*16 + l16) * SW_STRIDE + kk]);
        const short8 b2 = *(const short8*)(&sW[(2*16 + l16) * SW_STRIDE + kk]);
        const short8 b3 = *(const short8*)(&sW[(3*16 + l16) * SW_STRIDE + kk]);
        const int ci = h * 32 + quad * 8;
        short8 a0 = *(const short8*)(&sIn[(m0 + tap) * FSIN_STRIDE + ci]);
        short8 a1 = *(const short8*)(&sIn[(m1 + tap) * FSIN_STRIDE + ci]);
        if (!msk0) a0 = zero8;
        if (!msk1) a1 = zero8;
        acc[0][0] = __builtin_amdgcn_mfma_f32_16x16x32_bf16(a0,b0,acc[0][0],0,0,0);
        acc[0][1] = __builtin_amdgcn_mfma_f32_16x16x32_bf16(a0,b1,acc[0][1],0,0,0);
        acc[0][2] = __builtin_amdgcn_mfma_f32_16x16x32_bf16(a0,b2,acc[0][2],0,0,0);
        acc[0][3] = __builtin_amdgcn_mfma_f32_16x16x32_bf16(a0,b3,acc[0][3],0,0,0);
        acc[1][0] = __builtin_amdgcn_mfma_f32_16x16x32_bf16(a1,b0,acc[1][0],0,0,0);
        acc[1][1] = __builtin_amdgcn_mfma_f32_16x16x32_bf16(a1,b1,acc[1][1],0,0,0);
        acc[1][2] = __builtin_amdgcn_mfma_f32_16x16x32_bf16(a1,b2,acc[1][2],0,0,0);
        acc[1][3] = __builtin_amdgcn_mfma_f32_16x16x32_bf16(a1,b3,acc[1][3],0,0,0);
      }
    }
    #pragma unroll
    for (int mm = 0; mm < 2; ++mm) {
      const int lrow = l0 + wave * 32 + mm * 16 + quad * 4;
      #pragma unroll
      for (int reg = 0; reg < 4; ++reg) {
        float* orow = gout + ((size_t)(bL + lrow + reg) * NG + g) * OPG;
        #pragma unroll
        for (int nt = 0; nt < 4; ++nt)
          orow[nt * 16 + l16] = acc[mm][nt][reg];
      }
    }
  }
}

extern "C" void kernel_launch(void* const* d_in, const int* in_sizes, int n_in,
                              void* d_out, int out_size, void* d_ws, size_t ws_size,
                              hipStream_t stream) {
  (void)in_sizes; (void)n_in; (void)out_size;
  const float* gin  = (const float*)d_in[0];
  const int*   gpos = (const int*)d_in[1];
  const float* gwt  = (const float*)d_in[2];
  float*       gout = (float*)d_out;

  if (ws_size >= WFRAG_BYTES) {
    unsigned short* wfrag = (unsigned short*)d_ws;
    hipLaunchKernelGGL(wprep, dim3(160), dim3(256), 0, stream, gwt, wfrag);
    dim3 grid(LSEQ / ROWS, NG, 4);   // 32 x 16 x 4 = 2048 blocks
    hipLaunchKernelGGL(mconv_main, grid, dim3(256), 0, stream,
                       gin, gpos, wfrag, gout);
  } else {
    dim3 grid(LSEQ / fb::ROWS_PER_BLOCK, NG, 4);
    hipLaunchKernelGGL(mconv_f32_mfma, grid, dim3(256), 0, stream,
                       gin, gpos, gwt, gout);
  }
}